// Round 1
// baseline (483.014 us; speedup 1.0000x reference)
//
#include <hip/hip_runtime.h>

// LocNet2d: 3 locally-connected blocks + linear head.
// x:(128,3,32,32)  w1:(512,3,8,8,16)  w2:(512,512,2,2,16)  w3:(512,512,1,1,4)  beta:(512,1)
// L1: y1[b,o,p1,q1] = relu(sum_{c,f} x[b,c,p1*4+fi,q1*4+fj]*w1[o,c,p1,q1,f] / sqrt(48))
//     stored pre-patchified for L2: A2[s=p2*2+q2][b][o*16 + fi4*4 + fj4], p1=p2*4+fi4
// L2: per s: GEMM M=128 N=512 K=8192; y2 -> A3[b][o*4+s]
// L3: GEMM M=128 N=512 K=2048 -> y3[b][o]
// head: out[b] = sum_o y3[b][o]*beta[o] / sqrt(512)

__global__ __launch_bounds__(256) void l1_kernel(const float* __restrict__ x,
                                                 const float* __restrict__ w1,
                                                 float* __restrict__ A2) {
    // grid: (64 patches, 32 o-tiles, 8 b-tiles), block 256 = 16b x 16o
    const int pq = blockIdx.x;            // p1*8 + q1
    const int p1 = pq >> 3, q1 = pq & 7;
    const int o0 = blockIdx.y * 16;
    const int b0 = blockIdx.z * 16;
    __shared__ float xs[16][49];          // [b][k], pad 49 breaks bank aliasing
    __shared__ float ws[16][49];          // [o][k]
    const int t = threadIdx.x;
    for (int e = t; e < 768; e += 256) {
        int row = e / 48, k = e % 48;
        int c = k >> 4, f = k & 15, fi = (f >> 2), fj = (f & 3);
        xs[row][k] = x[((b0 + row) * 3 + c) * 1024 + (p1 * 4 + fi) * 32 + (q1 * 4 + fj)];
    }
    for (int e = t; e < 768; e += 256) {
        int row = e / 48, k = e % 48;
        int c = k >> 4, f = k & 15;
        ws[row][k] = w1[(o0 + row) * 3072 + c * 1024 + p1 * 128 + q1 * 16 + f];
    }
    __syncthreads();
    const int bb = t & 15, oo = t >> 4;
    float acc = 0.f;
#pragma unroll
    for (int k = 0; k < 48; ++k) acc += xs[bb][k] * ws[oo][k];
    acc = fmaxf(acc * 0.14433756729740643f, 0.f);  // 1/sqrt(48), relu
    const int o = o0 + oo, b = b0 + bb;
    const int p2 = p1 >> 2, fi4 = p1 & 3, q2 = q1 >> 2, fj4 = q1 & 3;
    A2[(size_t)((p2 * 2 + q2) * 128 + b) * 8192 + o * 16 + fi4 * 4 + fj4] = acc;
}

__global__ __launch_bounds__(256) void l2_kernel(const float* __restrict__ A2,
                                                 const float* __restrict__ w2,
                                                 float* __restrict__ A3) {
    // grid: (4 patches, 32 o-tiles, 8 b-tiles), block 256 = 16b x 16o
    const int s = blockIdx.x;
    const int o0 = blockIdx.y * 16;
    const int b0 = blockIdx.z * 16;
    const int p = s >> 1, q = s & 1;
    __shared__ float As[16][65];
    __shared__ float Bs[16][65];
    const float* __restrict__ Ab = A2 + (size_t)s * 128 * 8192;
    const int t = threadIdx.x;
    const int bb = t & 15, oo = t >> 4;
    float acc = 0.f;
    for (int k0 = 0; k0 < 8192; k0 += 64) {
        __syncthreads();
        for (int e = t; e < 1024; e += 256) {
            int row = e >> 6, kk = e & 63;
            As[row][kk] = Ab[(size_t)(b0 + row) * 8192 + k0 + kk];
        }
        for (int e = t; e < 1024; e += 256) {
            int row = e >> 6, kk = e & 63;
            int k = k0 + kk;
            int c = k >> 4, f = k & 15;
            Bs[row][kk] = w2[(size_t)(o0 + row) * 32768 + c * 64 + p * 32 + q * 16 + f];
        }
        __syncthreads();
#pragma unroll
        for (int kk = 0; kk < 64; ++kk) acc += As[bb][kk] * Bs[oo][kk];
    }
    acc = fmaxf(acc * 0.011048543456039805f, 0.f);  // 1/sqrt(8192), relu
    A3[(size_t)(b0 + bb) * 2048 + (o0 + oo) * 4 + s] = acc;
}

__global__ __launch_bounds__(256) void l3_kernel(const float* __restrict__ A3,
                                                 const float* __restrict__ w3,
                                                 float* __restrict__ y3) {
    // grid: (32 o-tiles, 8 b-tiles), block 256 = 16b x 16o
    const int o0 = blockIdx.x * 16;
    const int b0 = blockIdx.y * 16;
    __shared__ float As[16][65];
    __shared__ float Bs[16][65];
    const int t = threadIdx.x;
    const int bb = t & 15, oo = t >> 4;
    float acc = 0.f;
    for (int k0 = 0; k0 < 2048; k0 += 64) {
        __syncthreads();
        for (int e = t; e < 1024; e += 256) {
            int row = e >> 6, kk = e & 63;
            As[row][kk] = A3[(size_t)(b0 + row) * 2048 + k0 + kk];
            Bs[row][kk] = w3[(size_t)(o0 + row) * 2048 + k0 + kk];
        }
        __syncthreads();
#pragma unroll
        for (int kk = 0; kk < 64; ++kk) acc += As[bb][kk] * Bs[oo][kk];
    }
    acc = fmaxf(acc * 0.022097086912079608f, 0.f);  // 1/sqrt(2048), relu
    y3[(size_t)(b0 + bb) * 512 + (o0 + oo)] = acc;
}

__global__ __launch_bounds__(64) void out_kernel(const float* __restrict__ y3,
                                                 const float* __restrict__ beta,
                                                 float* __restrict__ out) {
    const int b = blockIdx.x;
    const int lane = threadIdx.x;
    float acc = 0.f;
#pragma unroll
    for (int o = lane; o < 512; o += 64) acc += y3[(size_t)b * 512 + o] * beta[o];
#pragma unroll
    for (int off = 32; off > 0; off >>= 1) acc += __shfl_down(acc, off);
    if (lane == 0) out[b] = acc * 0.044194173824159216f;  // 1/sqrt(512)
}

extern "C" void kernel_launch(void* const* d_in, const int* in_sizes, int n_in,
                              void* d_out, int out_size, void* d_ws, size_t ws_size,
                              hipStream_t stream) {
    const float* x    = (const float*)d_in[0];
    const float* w1   = (const float*)d_in[1];
    const float* w2   = (const float*)d_in[2];
    const float* w3   = (const float*)d_in[3];
    const float* beta = (const float*)d_in[4];
    float* out = (float*)d_out;

    float* A2 = (float*)d_ws;            // 4*128*8192 = 4,194,304 floats (16 MB)
    float* A3 = A2 + 4 * 128 * 8192;     // 128*2048   =   262,144 floats (1 MB)
    float* y3 = A3 + 128 * 2048;         // 128*512    =    65,536 floats (256 KB)

    l1_kernel<<<dim3(64, 32, 8), 256, 0, stream>>>(x, w1, A2);
    l2_kernel<<<dim3(4, 32, 8), 256, 0, stream>>>(A2, w2, A3);
    l3_kernel<<<dim3(32, 8), 256, 0, stream>>>(A3, w3, y3);
    out_kernel<<<128, 64, 0, stream>>>(y3, beta, out);
}

// Round 2
// 74.036 us; speedup vs baseline: 6.5240x; 6.5240x over previous
//
#include <hip/hip_runtime.h>

// LocNet2d on MFMA fp16: 3 locally-connected blocks + linear head.
// L1: per-patch GEMM (64 patches, M=128,N=512,K=48 pad 64) -> A2 fp16 [s][b][k2=o*16+g]
// L2: per-s GEMM M=128,N=512,K=8192, splitK=4 -> P2 fp32 -> reduce -> A3 fp16 [b][o*4+s]
// L3: GEMM M=128,N=512,K=2048, splitK=4 -> P3 fp32 -> reduce -> y3 fp32
// head: out[b] = sum_o y3[b][o]*beta[o] / sqrt(512)

typedef _Float16 f16;
typedef _Float16 half8 __attribute__((ext_vector_type(8)));
typedef _Float16 half4 __attribute__((ext_vector_type(4)));
typedef float f32x4 __attribute__((ext_vector_type(4)));

// LDS half-index swizzle: rows are 64 halves (128 B); XOR bits 3-5 with row&7
// spreads the 8 16-B slots across banks (G4 fix for 128-B-stride conflicts).
#define SWZ(r, c) ((((r) << 6) + (c)) ^ (((r) & 7) << 3))

__global__ __launch_bounds__(256) void l1_mfma(const float* __restrict__ x,
                                               const float* __restrict__ w1,
                                               f16* __restrict__ A2) {
  // grid: (64 patches pq, 8 o-tiles). Block: 256 thr = 4 waves, tile 128b x 64o.
  const int pq = blockIdx.x, p1 = pq >> 3, q1 = pq & 7;
  const int o0 = blockIdx.y << 6;
  __shared__ __align__(16) f16 Xs[128 * 64];
  __shared__ __align__(16) f16 Ws[64 * 64];
  const int t = threadIdx.x;
  // stage X: 128 rows x 16 chunks of 4 halves (k = j*4; j>=12 -> zero pad)
#pragma unroll
  for (int i = 0; i < 8; ++i) {
    int idx = (i << 8) + t, row = idx >> 4, j = idx & 15;
    half4 h = {0, 0, 0, 0};
    if (j < 12) {
      float4 v = *(const float4*)(x + ((size_t)row * 3 + (j >> 2)) * 1024 +
                                  (p1 * 4 + (j & 3)) * 32 + q1 * 4);
      h[0] = (f16)v.x; h[1] = (f16)v.y; h[2] = (f16)v.z; h[3] = (f16)v.w;
    }
    *(half4*)&Xs[SWZ(row, j << 2)] = h;
  }
#pragma unroll
  for (int i = 0; i < 4; ++i) {
    int idx = (i << 8) + t, row = idx >> 4, j = idx & 15;
    half4 h = {0, 0, 0, 0};
    if (j < 12) {
      float4 v = *(const float4*)(w1 + (size_t)(o0 + row) * 3072 + (j >> 2) * 1024 +
                                  p1 * 128 + q1 * 16 + (j & 3) * 4);
      h[0] = (f16)v.x; h[1] = (f16)v.y; h[2] = (f16)v.z; h[3] = (f16)v.w;
    }
    *(half4*)&Ws[SWZ(row, j << 2)] = h;
  }
  __syncthreads();
  const int w = t >> 6, lane = t & 63;
  const int wr = w >> 1, wc = w & 1;
  const int frow = lane & 15, fk = (lane >> 4) << 3;
  f32x4 acc[4][2] = {};
#pragma unroll
  for (int ks = 0; ks < 2; ++ks) {
    const int col = (ks << 5) + fk;
    half8 a[4], b[2];
#pragma unroll
    for (int mi = 0; mi < 4; ++mi)
      a[mi] = *(const half8*)&Xs[SWZ(wr * 64 + mi * 16 + frow, col)];
#pragma unroll
    for (int ni = 0; ni < 2; ++ni)
      b[ni] = *(const half8*)&Ws[SWZ(wc * 32 + ni * 16 + frow, col)];
#pragma unroll
    for (int mi = 0; mi < 4; ++mi)
#pragma unroll
      for (int ni = 0; ni < 2; ++ni)
        acc[mi][ni] = __builtin_amdgcn_mfma_f32_16x16x32_f16(a[mi], b[ni], acc[mi][ni], 0, 0, 0);
  }
  const int s2 = ((p1 >> 2) << 1) + (q1 >> 2);
  const int g = ((p1 & 3) << 2) + (q1 & 3);
  f16* A2b = A2 + (size_t)s2 * 128 * 8192;
#pragma unroll
  for (int mi = 0; mi < 4; ++mi)
#pragma unroll
    for (int ni = 0; ni < 2; ++ni)
#pragma unroll
      for (int r = 0; r < 4; ++r) {
        int gm = wr * 64 + mi * 16 + (lane >> 4) * 4 + r;
        int go = o0 + wc * 32 + ni * 16 + (lane & 15);
        float v = fmaxf(acc[mi][ni][r] * 0.14433756729740643f, 0.f);  // 1/sqrt(48)
        A2b[(size_t)gm * 8192 + go * 16 + g] = (f16)v;
      }
}

template <int MODE>  // 0: L2 (w2 gather, splitK over 8192), 1: L3 (contiguous w3)
__global__ __launch_bounds__(256) void gemm_f16(const f16* __restrict__ A,
                                                const float* __restrict__ W,
                                                float* __restrict__ P) {
  __shared__ __align__(16) f16 As[64 * 64];
  __shared__ __align__(16) f16 Bs[64 * 64];
  const int t = threadIdx.x;
  const int bid = blockIdx.x;
  int kc, s, m, n, iters, AK, SROW, kbase, poff;
  if (MODE == 0) {
    kc = bid >> 6; s = (bid >> 4) & 3; m = (bid >> 3) & 1; n = bid & 7;
    iters = 32; AK = 8192; SROW = 32768; kbase = kc << 11;
    poff = ((s >> 1) << 5) + ((s & 1) << 4);  // p*32 + q*16
  } else {
    kc = bid >> 4; s = 0; m = (bid >> 3) & 1; n = bid & 7;
    iters = 8; AK = 2048; SROW = 2048; kbase = kc << 9; poff = 0;
  }
  const f16* Ab = A + ((size_t)(MODE == 0 ? s * 128 : 0) + m * 64) * AK + kbase;
  const int o0 = n << 6;
  const int w = t >> 6, lane = t & 63;
  const int wr = w >> 1, wc = w & 1;
  const int frow = lane & 15, fk = (lane >> 4) << 3;
  f32x4 acc[2][2] = {};
  for (int it = 0; it < iters; ++it) {
    const int k0 = it << 6;
    __syncthreads();
    // A: fp16 global -> LDS copy, 2x16B per thread
#pragma unroll
    for (int i = 0; i < 2; ++i) {
      int idx = (i << 8) + t, row = idx >> 3, sl = idx & 7;
      uint4 v = *(const uint4*)(Ab + (size_t)row * AK + k0 + (sl << 3));
      *(uint4*)&As[SWZ(row, sl << 3)] = v;
    }
    // B: fp32 global -> cvt fp16 -> LDS, 4x float4 per thread
#pragma unroll
    for (int i = 0; i < 4; ++i) {
      int idx = (i << 8) + t, row = idx >> 4, c4 = idx & 15;
      int k = kbase + k0 + (c4 << 2);
      const float* src = (MODE == 0)
          ? W + (size_t)(o0 + row) * SROW + ((size_t)(k >> 4) << 6) + poff + (k & 15)
          : W + (size_t)(o0 + row) * SROW + k;
      float4 v = *(const float4*)src;
      half4 h;
      h[0] = (f16)v.x; h[1] = (f16)v.y; h[2] = (f16)v.z; h[3] = (f16)v.w;
      *(half4*)&Bs[SWZ(row, c4 << 2)] = h;
    }
    __syncthreads();
#pragma unroll
    for (int ks = 0; ks < 2; ++ks) {
      const int col = (ks << 5) + fk;
      half8 a0 = *(const half8*)&As[SWZ(wr * 32 + frow, col)];
      half8 a1 = *(const half8*)&As[SWZ(wr * 32 + 16 + frow, col)];
      half8 b0 = *(const half8*)&Bs[SWZ(wc * 32 + frow, col)];
      half8 b1 = *(const half8*)&Bs[SWZ(wc * 32 + 16 + frow, col)];
      acc[0][0] = __builtin_amdgcn_mfma_f32_16x16x32_f16(a0, b0, acc[0][0], 0, 0, 0);
      acc[0][1] = __builtin_amdgcn_mfma_f32_16x16x32_f16(a0, b1, acc[0][1], 0, 0, 0);
      acc[1][0] = __builtin_amdgcn_mfma_f32_16x16x32_f16(a1, b0, acc[1][0], 0, 0, 0);
      acc[1][1] = __builtin_amdgcn_mfma_f32_16x16x32_f16(a1, b1, acc[1][1], 0, 0, 0);
    }
  }
  float* Pb = P + ((size_t)(MODE == 0 ? (kc << 2) + s : kc) * 128) * 512;
#pragma unroll
  for (int mi = 0; mi < 2; ++mi)
#pragma unroll
    for (int ni = 0; ni < 2; ++ni)
#pragma unroll
      for (int r = 0; r < 4; ++r) {
        int gm = (m << 6) + wr * 32 + mi * 16 + (lane >> 4) * 4 + r;
        int gn = o0 + wc * 32 + ni * 16 + (lane & 15);
        Pb[(size_t)gm * 512 + gn] = acc[mi][ni][r];
      }
}

__global__ __launch_bounds__(256) void reduce2(const float* __restrict__ P2,
                                               f16* __restrict__ A3) {
  int idx = blockIdx.x * 256 + threadIdx.x;  // 262144 = 4s*128b*512o
  int o = idx & 511, b = (idx >> 9) & 127, s = idx >> 16;
  float v = 0.f;
#pragma unroll
  for (int kc = 0; kc < 4; ++kc) v += P2[(size_t)((kc << 2) + s) * 65536 + b * 512 + o];
  v = fmaxf(v * 0.011048543456039805f, 0.f);  // 1/sqrt(8192)
  A3[(size_t)b * 2048 + o * 4 + s] = (f16)v;
}

__global__ __launch_bounds__(256) void reduce3(const float* __restrict__ P3,
                                               float* __restrict__ y3) {
  int idx = blockIdx.x * 256 + threadIdx.x;  // 65536
  int o = idx & 511, b = idx >> 9;
  float v = 0.f;
#pragma unroll
  for (int kc = 0; kc < 4; ++kc) v += P3[(size_t)kc * 65536 + b * 512 + o];
  y3[(size_t)b * 512 + o] = fmaxf(v * 0.022097086912079608f, 0.f);  // 1/sqrt(2048)
}

__global__ __launch_bounds__(64) void out_kernel(const float* __restrict__ y3,
                                                 const float* __restrict__ beta,
                                                 float* __restrict__ out) {
  const int b = blockIdx.x;
  const int lane = threadIdx.x;
  float acc = 0.f;
#pragma unroll
  for (int o = lane; o < 512; o += 64) acc += y3[(size_t)b * 512 + o] * beta[o];
#pragma unroll
  for (int off = 32; off > 0; off >>= 1) acc += __shfl_down(acc, off);
  if (lane == 0) out[b] = acc * 0.044194173824159216f;  // 1/sqrt(512)
}

extern "C" void kernel_launch(void* const* d_in, const int* in_sizes, int n_in,
                              void* d_out, int out_size, void* d_ws, size_t ws_size,
                              hipStream_t stream) {
  const float* x    = (const float*)d_in[0];
  const float* w1   = (const float*)d_in[1];
  const float* w2   = (const float*)d_in[2];
  const float* w3   = (const float*)d_in[3];
  const float* beta = (const float*)d_in[4];
  float* out = (float*)d_out;

  char* wsb = (char*)d_ws;
  f16*   A2 = (f16*)wsb;                                   // 8 MiB: 4*128*8192 fp16
  float* P2 = (float*)(wsb + (8u << 20));                  // 4 MiB: 16*128*512 fp32
  f16*   A3 = (f16*)(wsb + (12u << 20));                   // 0.5 MiB: 128*2048 fp16
  float* P3 = (float*)(wsb + (12u << 20) + (512u << 10));  // 1 MiB: 4*128*512 fp32
  float* y3 = (float*)(wsb + (13u << 20) + (512u << 10));  // 0.25 MiB: 128*512 fp32

  l1_mfma<<<dim3(64, 8), 256, 0, stream>>>(x, w1, A2);
  gemm_f16<0><<<256, 256, 0, stream>>>(A2, w2, P2);
  reduce2<<<1024, 256, 0, stream>>>(P2, A3);
  gemm_f16<1><<<64, 256, 0, stream>>>(A3, w3, P3);
  reduce3<<<256, 256, 0, stream>>>(P3, y3);
  out_kernel<<<128, 64, 0, stream>>>(y3, beta, out);
}